// Round 13
// baseline (824.207 us; speedup 1.0000x reference)
//
#include <hip/hip_runtime.h>

#define Q 2048
#define NTRAIN 65536
#define D 768
#define KNN 7

#define BM 128               // queries per block
#define BN 256               // trains per block
#define BKB 128              // K-tile in BYTES = elements (fp8); 6 K-steps
#define KT (D / BKB)         // 6
#define NCT 512              // virtual 128-train tiles (cand layout, unchanged)
#define NBT (NTRAIN / BN)    // 256 grid column tiles
#define TSEL 8               // candidates kept per (row, 128-tile)

typedef __attribute__((ext_vector_type(4))) int   i32x4;
typedef __attribute__((ext_vector_type(8))) int   i32x8;
typedef __attribute__((ext_vector_type(4))) float f32x4;

// ---- ws layout (bytes) ----
static constexpr size_t XB_OFF   = 0;
static constexpr size_t TB_OFF   = XB_OFF + (size_t)Q * D;
static constexpr size_t TSQ_OFF  = TB_OFF + (size_t)NTRAIN * D;
static constexpr size_t CAND_OFF = TSQ_OFF + (size_t)NTRAIN * 4;

__device__ __forceinline__ unsigned pack32(float f) {
    unsigned u = __float_as_uint(f);
    return u ^ (unsigned)(((int)u >> 31) | 0x80000000);    // monotone map
}

__device__ __forceinline__ void gload16(const void* g, void* l) {
    __builtin_amdgcn_global_load_lds(
        (const __attribute__((address_space(1))) unsigned*)g,
        (__attribute__((address_space(3))) unsigned*)l, 16, 0, 0);
}

__device__ __forceinline__ unsigned long long shfl_xor64(unsigned long long p, int off) {
    unsigned hi = (unsigned)(p >> 32), lo = (unsigned)p;
    unsigned ohi = (unsigned)__shfl_xor((int)hi, off);
    unsigned olo = (unsigned)__shfl_xor((int)lo, off);
    return ((unsigned long long)ohi << 32) | olo;
}

// ---------------- Kernel 1: fused fp32 -> fp8(e4m3) + row sq-norms ----------------
__global__ void prep_kernel(const float* __restrict__ X,
                            const float* __restrict__ Xt,
                            unsigned* __restrict__ Xb8,
                            unsigned* __restrict__ Tb8,
                            float* __restrict__ tsq) {
    __shared__ float red[3];
    const int b = blockIdx.x;
    const int t = threadIdx.x;
    const bool isX = (b < Q);
    const int row = isX ? b : b - Q;
    const float* src = isX ? X : Xt;
    unsigned* dst = isX ? Xb8 : Tb8;
    float4 v = reinterpret_cast<const float4*>(src)[(size_t)row * (D / 4) + t];
    unsigned u;
    u = __builtin_amdgcn_cvt_pk_fp8_f32(v.x, v.y, 0, false);   // bytes 0,1
    u = __builtin_amdgcn_cvt_pk_fp8_f32(v.z, v.w, u, true);    // bytes 2,3
    dst[(size_t)row * (D / 4) + t] = u;
    if (!isX) {
        float s = v.x * v.x + v.y * v.y + v.z * v.z + v.w * v.w;
#pragma unroll
        for (int off = 32; off; off >>= 1) s += __shfl_down(s, off);
        if ((t & 63) == 0) red[t >> 6] = s;
        __syncthreads();
        if (t == 0) tsq[row] = red[0] + red[1] + red[2];
    }
}

// ---------------- Kernel 2: MX-fp8 MFMA GEMM 128x256, 4 waves of 64q x 128t ----------------
// Swapped operands (D = S^T, query = lane&15). Per wave per K-step: 32 MFMA / 24 ds_read_b128
// (vs R9's 16/16) -> MFMA:LDS ratio 1.33. Same verified 2-barrier structure, 4-wave blocks,
// 48 KB LDS -> 3 blocks/CU (keeps cross-block overlap; R11's 8-wave/2-block config failed).
__global__ void __launch_bounds__(256, 3) knn_gemm_kernel(
    const unsigned char* __restrict__ Xb8, const unsigned char* __restrict__ Tb8,
    const float* __restrict__ tsq, unsigned* __restrict__ cand) {
    // smem: [0,16384) A-tile fp8[128][128] (queries), [16384,49152) B-tile fp8[256][128] (trains)
    __shared__ __align__(16) char smem[49152];
    const int tid  = threadIdx.x;
    const int wave = tid >> 6, lane = tid & 63;

    // ---- T1 XCD-aware swizzle (bijective over 4096 blocks; same-XCD shares colTile) ----
    const int flat = blockIdx.y * 16 + blockIdx.x;         // [0, 4096)
    const int rowTile = (flat >> 3) & 15;                  // [0, 16)
    const int colTile = (flat & 7) * 32 + (flat >> 7);     // [0, 256)

    const int wr = wave >> 1, wc = wave & 1;               // query-half, train-half

    const f32x4 zero = {0.f, 0.f, 0.f, 0.f};
    f32x4 acc[8][4];          // [mt][nq]: 8 train-16-blocks x 4 query-16-blocks
#pragma unroll
    for (int m = 0; m < 8; m++)
#pragma unroll
        for (int n = 0; n < 4; n++) acc[m][n] = zero;

    // ---- frag bases: row&7 == lane&7 for every frag -> single base + imm offsets ----
    const int gp = (lane >> 4) * 2;
    const int g  = gp ^ (lane & 7);
    const int g2 = (gp + 1) ^ (lane & 7);
    const int aBaseL = (wr * 64 + (lane & 15)) * 128 + g * 16;
    const int aBaseH = (wr * 64 + (lane & 15)) * 128 + g2 * 16;
    const int bBaseL = 16384 + (wc * 128 + (lane & 15)) * 128 + g * 16;
    const int bBaseH = 16384 + (wc * 128 + (lane & 15)) * 128 + g2 * 16;

    // ---- staging: 256 thr x 16 B = 4 KB sweep = 32 rows; A 4 chunks, B 8 chunks ----
    const int s_row = wave * 8 + (lane >> 3);                  // [0, 32)
    const int s_colB = (((lane & 7) ^ (s_row & 7)) * 16);      // pre-swizzled source granule
    const unsigned char* pA[4];
    const unsigned char* pB[8];
#pragma unroll
    for (int c = 0; c < 4; c++)
        pA[c] = Xb8 + (size_t)(rowTile * BM + c * 32 + s_row) * D + s_colB;
#pragma unroll
    for (int c = 0; c < 8; c++)
        pB[c] = Tb8 + (size_t)(colTile * BN + c * 32 + s_row) * D + s_colB;

#pragma unroll
    for (int kt = 0; kt < KT; ++kt) {
        const int k0 = kt * BKB;
        __syncthreads();                 // previous step's ds_reads complete
#pragma unroll
        for (int c = 0; c < 4; ++c)
            gload16(pA[c] + k0, smem + c * 4096 + wave * 1024);
#pragma unroll
        for (int c = 0; c < 8; ++c)
            gload16(pB[c] + k0, smem + 16384 + c * 4096 + wave * 1024);
        __syncthreads();                 // tile ready
        i32x8 a[4];
#pragma unroll
        for (int n = 0; n < 4; n++) {
            i32x4 lo = *(const i32x4*)(smem + aBaseL + n * 2048);
            i32x4 hi = *(const i32x4*)(smem + aBaseH + n * 2048);
            a[n] = (i32x8){lo[0], lo[1], lo[2], lo[3], hi[0], hi[1], hi[2], hi[3]};
        }
#pragma unroll
        for (int mt = 0; mt < 8; mt++) {
            i32x4 lo = *(const i32x4*)(smem + bBaseL + mt * 2048);
            i32x4 hi = *(const i32x4*)(smem + bBaseH + mt * 2048);
            i32x8 b = (i32x8){lo[0], lo[1], lo[2], lo[3], hi[0], hi[1], hi[2], hi[3]};
            // SWAPPED: train-frag as A-operand, query-frag as B-operand -> D = S^T
#pragma unroll
            for (int n = 0; n < 4; n++)
                acc[mt][n] = __builtin_amdgcn_mfma_scale_f32_16x16x128_f8f6f4(
                    b, a[n], acc[mt][n],
                    0, 0, 0, 0x7F7F7F7Fu, 0, 0x7F7F7F7Fu);
        }
    }
    // no post-loop barrier needed: no further LDS use

    // ---- register epilogue: per-query top-4 per 64-train half (2 halves) ----
    const int tq0 = colTile * BN + wc * 128 + (lane >> 4) * 4;
    const int qrow = rowTile * BM + wr * 64 + lane;   // owner lane's query (when lane>>4==nq)
    const int vt = colTile * 2 + wc;                  // virtual 128-train tile
    uint4 outh[2];
#pragma unroll
    for (int h = 0; h < 2; h++) {
        const int tqh = tq0 + h * 64;
        float4 tsvh[4];
#pragma unroll
        for (int j = 0; j < 4; j++)
            tsvh[j] = *reinterpret_cast<const float4*>(tsq + tqh + j * 16);
#pragma unroll
        for (int nq = 0; nq < 4; nq++) {
            unsigned m1 = ~0u, m2 = ~0u, m3 = ~0u, m4 = ~0u;
#pragma unroll
            for (int j = 0; j < 4; j++) {
                const float* tv = (const float*)&tsvh[j];
#pragma unroll
                for (int r = 0; r < 4; r++) {
                    float key = fmaf(-2.f, acc[h * 4 + j][nq][r], tv[r]);
                    unsigned v = (pack32(key) & 0xFFFF0000u) | (unsigned)(tqh + j * 16 + r);
                    unsigned t0, t1, t2;
                    t0 = max(m1, v);  m1 = min(m1, v);
                    t1 = max(m2, t0); m2 = min(m2, t0);
                    t2 = max(m3, t1); m3 = min(m3, t1);
                    m4 = min(m4, t2);
                }
            }
            // butterfly merges across the 4 lane-groups holding this query's trains
#pragma unroll
            for (int off = 16; off <= 32; off <<= 1) {
                unsigned o1 = (unsigned)__shfl_xor((int)m1, off);
                unsigned o2 = (unsigned)__shfl_xor((int)m2, off);
                unsigned o3 = (unsigned)__shfl_xor((int)m3, off);
                unsigned o4 = (unsigned)__shfl_xor((int)m4, off);
                unsigned a1 = min(m1, o4), a2 = min(m2, o3);
                unsigned a3 = min(m3, o2), a4 = min(m4, o1);
                unsigned t;
                t = min(a1, a3); a3 = max(a1, a3); a1 = t;
                t = min(a2, a4); a4 = max(a2, a4); a2 = t;
                t = min(a1, a2); a2 = max(a1, a2); a1 = t;
                t = min(a3, a4); a4 = max(a3, a4); a3 = t;
                m1 = a1; m2 = a2; m3 = a3; m4 = a4;
            }
            if ((lane >> 4) == nq) outh[h] = (uint4){m1, m2, m3, m4};
        }
    }
    unsigned* dst = cand + ((size_t)qrow * NCT + vt) * TSEL;
    *reinterpret_cast<uint4*>(dst)     = outh[0];
    *reinterpret_cast<uint4*>(dst + 4) = outh[1];
}

// ---------------- Kernel 3: per-wave top-8 -> exact fp32 re-rank (32) -> top-7 mean ----------------
__global__ void __launch_bounds__(256) knn_reduce_kernel(
    const float* __restrict__ X, const float* __restrict__ Xt,
    const float* __restrict__ tsq, const float* __restrict__ y,
    const unsigned* __restrict__ cand, float* __restrict__ out) {
    __shared__ float xrow[D];
    __shared__ float red[4];
    __shared__ unsigned sel[32];
    __shared__ float exd[32];
    __shared__ unsigned exi[32];
    __shared__ float ys[32];
    const int q = blockIdx.x;
    const int tid = threadIdx.x;
    const int lane = tid & 63, wave = tid >> 6;

    if (tid < D / 4)
        ((float4*)xrow)[tid] = ((const float4*)(X + (size_t)q * D))[tid];

    const unsigned* cq = cand + (size_t)q * (NCT * TSEL) + wave * 1024 + lane * 4;
    unsigned v[16];
    {
        uint4 a = *(const uint4*)(cq);
        uint4 b = *(const uint4*)(cq + 256);
        uint4 c = *(const uint4*)(cq + 512);
        uint4 d = *(const uint4*)(cq + 768);
        v[0] = a.x;  v[1] = a.y;  v[2] = a.z;  v[3] = a.w;
        v[4] = b.x;  v[5] = b.y;  v[6] = b.z;  v[7] = b.w;
        v[8] = c.x;  v[9] = c.y;  v[10] = c.z; v[11] = c.w;
        v[12] = d.x; v[13] = d.y; v[14] = d.z; v[15] = d.w;
    }

#pragma unroll
    for (int r = 0; r < 8; ++r) {
        unsigned lm = v[0];
#pragma unroll
        for (int i = 1; i < 16; ++i) lm = min(lm, v[i]);
        unsigned wm = lm;
#pragma unroll
        for (int off = 1; off < 64; off <<= 1) {
            unsigned o = (unsigned)__shfl_xor((int)wm, off);
            wm = min(wm, o);
        }
        if (lane == 0) sel[wave * 8 + r] = wm;
        if (lm == wm) {
            bool done = false;
#pragma unroll
            for (int i = 0; i < 16; ++i)
                if (!done && v[i] == wm) { v[i] = 0xFFFFFFFFu; done = true; }
        }
    }
    __syncthreads();

    float xs = 0.f;
#pragma unroll
    for (int j = 0; j < 3; j++) { float t = xrow[tid + j * 256]; xs = fmaf(t, t, xs); }
#pragma unroll
    for (int off = 32; off; off >>= 1) xs += __shfl_down(xs, off);
    if (lane == 0) red[wave] = xs;
    __syncthreads();
    const float xsqs = red[0] + red[1] + red[2] + red[3];

    {
        const int c = tid >> 3, p = tid & 7;
        const unsigned id = sel[c] & 0xFFFFu;
        const float4* t4 = (const float4*)(Xt + (size_t)id * D);
        const float4* x4 = (const float4*)xrow;
        float s = 0.f;
#pragma unroll
        for (int k = 0; k < 24; ++k) {
            float4 a = x4[p + 8 * k];
            float4 b = t4[p + 8 * k];
            s = fmaf(a.x, b.x, fmaf(a.y, b.y, fmaf(a.z, b.z, fmaf(a.w, b.w, s))));
        }
        s += __shfl_xor(s, 1); s += __shfl_xor(s, 2); s += __shfl_xor(s, 4);
        if (p == 0) {
            float d2 = xsqs + tsq[id] - 2.f * s;
            exd[c] = sqrtf(fmaxf(d2, 0.f));
            exi[c] = id;
            ys[c] = y[id];
        }
    }
    __syncthreads();

    if (wave == 0) {
        unsigned long long p;
        float myy = 0.f;
        if (lane < 32) {
            p = ((unsigned long long)pack32(exd[lane]) << 32) | exi[lane];
            myy = ys[lane];
        } else {
            p = ~0ull;
        }
        float acc = 0.f;
        for (int r = 0; r < KNN; ++r) {
            unsigned long long m = p;
#pragma unroll
            for (int off = 1; off < 64; off <<= 1) {
                unsigned long long o = shfl_xor64(m, off);
                m = o < m ? o : m;
            }
            if (p == m) { acc += myy; p = ~0ull; }
        }
#pragma unroll
        for (int off = 32; off; off >>= 1) acc += __shfl_down(acc, off);
        if (lane == 0) out[q] = acc / 7.0f;
    }
}

extern "C" void kernel_launch(void* const* d_in, const int* in_sizes, int n_in,
                              void* d_out, int out_size, void* d_ws, size_t ws_size,
                              hipStream_t stream) {
    const float* X  = (const float*)d_in[0];
    const float* Xt = (const float*)d_in[1];
    const float* y  = (const float*)d_in[2];
    float* out = (float*)d_out;
    char* ws = (char*)d_ws;
    unsigned* Xb8 = (unsigned*)(ws + XB_OFF);
    unsigned* Tb8 = (unsigned*)(ws + TB_OFF);
    float* tsq = (float*)(ws + TSQ_OFF);
    unsigned* cand = (unsigned*)(ws + CAND_OFF);

    prep_kernel<<<dim3(Q + NTRAIN), dim3(192), 0, stream>>>(X, Xt, Xb8, Tb8, tsq);
    knn_gemm_kernel<<<dim3(Q / BM, NBT), dim3(256), 0, stream>>>(
        (const unsigned char*)Xb8, (const unsigned char*)Tb8, tsq, cand);
    knn_reduce_kernel<<<dim3(Q), dim3(256), 0, stream>>>(X, Xt, tsq, y, cand, out);
}

// Round 14
// 194.161 us; speedup vs baseline: 4.2450x; 4.2450x over previous
//
#include <hip/hip_runtime.h>

#define Q 2048
#define NTRAIN 65536
#define D 768
#define KNN 7

#define BM 128
#define BN 128
#define BKB 128              // K-tile in BYTES = elements (fp8); 6 K-steps
#define KT (D / BKB)         // 6
#define NCT (NTRAIN / BN)    // 512 column tiles
#define TSEL 8               // candidates kept per (row, tile)

typedef __attribute__((ext_vector_type(4))) int   i32x4;
typedef __attribute__((ext_vector_type(8))) int   i32x8;
typedef __attribute__((ext_vector_type(4))) float f32x4;

// ---- ws layout (bytes) ----
static constexpr size_t XB_OFF   = 0;
static constexpr size_t TB_OFF   = XB_OFF + (size_t)Q * D;
static constexpr size_t TSQ_OFF  = TB_OFF + (size_t)NTRAIN * D;
static constexpr size_t CAND_OFF = TSQ_OFF + (size_t)NTRAIN * 4;

__device__ __forceinline__ unsigned pack32(float f) {
    unsigned u = __float_as_uint(f);
    return u ^ (unsigned)(((int)u >> 31) | 0x80000000);    // monotone map
}

__device__ __forceinline__ void gload16(const void* g, void* l) {
    __builtin_amdgcn_global_load_lds(
        (const __attribute__((address_space(1))) unsigned*)g,
        (__attribute__((address_space(3))) unsigned*)l, 16, 0, 0);
}

__device__ __forceinline__ unsigned long long shfl_xor64(unsigned long long p, int off) {
    unsigned hi = (unsigned)(p >> 32), lo = (unsigned)p;
    unsigned ohi = (unsigned)__shfl_xor((int)hi, off);
    unsigned olo = (unsigned)__shfl_xor((int)lo, off);
    return ((unsigned long long)ohi << 32) | olo;
}

// ---------------- Kernel 1: fused fp32 -> fp8(e4m3) + row sq-norms ----------------
__global__ void prep_kernel(const float* __restrict__ X,
                            const float* __restrict__ Xt,
                            unsigned* __restrict__ Xb8,
                            unsigned* __restrict__ Tb8,
                            float* __restrict__ tsq) {
    __shared__ float red[3];
    const int b = blockIdx.x;
    const int t = threadIdx.x;
    const bool isX = (b < Q);
    const int row = isX ? b : b - Q;
    const float* src = isX ? X : Xt;
    unsigned* dst = isX ? Xb8 : Tb8;
    float4 v = reinterpret_cast<const float4*>(src)[(size_t)row * (D / 4) + t];
    unsigned u;
    u = __builtin_amdgcn_cvt_pk_fp8_f32(v.x, v.y, 0, false);   // bytes 0,1
    u = __builtin_amdgcn_cvt_pk_fp8_f32(v.z, v.w, u, true);    // bytes 2,3
    dst[(size_t)row * (D / 4) + t] = u;
    if (!isX) {
        float s = v.x * v.x + v.y * v.y + v.z * v.z + v.w * v.w;
#pragma unroll
        for (int off = 32; off; off >>= 1) s += __shfl_down(s, off);
        if ((t & 63) == 0) red[t >> 6] = s;
        __syncthreads();
        if (t == 0) tsq[row] = red[0] + red[1] + red[2];
    }
}

// ---------------- Kernel 2: MX-fp8 MFMA GEMM, swapped operands + register epilogue ----------------
// D = S^T: D-row = train (from B-frag as A-operand), D-col = query = lane&15.
// Per lane: 4 query-blocks x 16 trains -> per-query top-4-of-64 fully in registers.
// Verified optimum (R9): 4-wave blocks, 32 KB LDS, 3+ blocks/CU; all structural variants
// (bigger tiles, dbuf, A-from-global, 64x128 acc) regressed — do not revisit.
__global__ void __launch_bounds__(256, 3) knn_gemm_kernel(
    const unsigned char* __restrict__ Xb8, const unsigned char* __restrict__ Tb8,
    const float* __restrict__ tsq, unsigned* __restrict__ cand) {
    // smem: [0,16384) A-tile fp8[128][128] (queries), [16384,32768) B-tile (trains)
    __shared__ __align__(16) char smem[32768];
    const int tid  = threadIdx.x;
    const int wave = tid >> 6, lane = tid & 63;

    // ---- T1 XCD-aware swizzle (bijective, verified R5) ----
    const int flat = blockIdx.y * 16 + blockIdx.x;
    const int rowTile = (flat >> 3) & 15;
    const int colTile = (flat & 7) * 64 + (flat >> 7);

    const int wr = wave >> 1, wc = wave & 1;

    const f32x4 zero = {0.f, 0.f, 0.f, 0.f};
    f32x4 acc[4][4];          // acc[mt][nq]: mt = train-block, nq = query-block
#pragma unroll
    for (int m = 0; m < 4; m++)
#pragma unroll
        for (int n = 0; n < 4; n++) acc[m][n] = zero;

    // ---- kt-invariant swizzled frag byte-offsets ----
    int aOffL[4], aOffH[4], bOffL[4], bOffH[4];
    const int gp = (lane >> 4) * 2;
#pragma unroll
    for (int m = 0; m < 4; m++) {
        const int rowA = wr * 64 + m * 16 + (lane & 15);     // query rows
        const int rowB = wc * 64 + m * 16 + (lane & 15);     // train rows
        aOffL[m] = rowA * 128 + ((gp       ^ (rowA & 7)) * 16);
        aOffH[m] = rowA * 128 + (((gp + 1) ^ (rowA & 7)) * 16);
        bOffL[m] = 16384 + rowB * 128 + ((gp       ^ (rowB & 7)) * 16);
        bOffH[m] = 16384 + rowB * 128 + (((gp + 1) ^ (rowB & 7)) * 16);
    }

    const int s_row = wave * 8 + (lane >> 3);
    const int s_colB = (((lane & 7) ^ (s_row & 7)) * 16);
    const unsigned char* pA[4];
    const unsigned char* pB[4];
#pragma unroll
    for (int c = 0; c < 4; c++) {
        pA[c] = Xb8 + (size_t)(rowTile * BM + c * 32 + s_row) * D + s_colB;
        pB[c] = Tb8 + (size_t)(colTile * BN + c * 32 + s_row) * D + s_colB;
    }
    char* Asm = smem;
    char* Bsm = smem + 16384;

#pragma unroll
    for (int kt = 0; kt < KT; ++kt) {
        const int k0 = kt * BKB;
        __syncthreads();
#pragma unroll
        for (int c = 0; c < 4; ++c) {
            gload16(pA[c] + k0, Asm + c * 4096 + wave * 1024);
            gload16(pB[c] + k0, Bsm + c * 4096 + wave * 1024);
        }
        __syncthreads();
        i32x8 a[4], b[4];
#pragma unroll
        for (int m = 0; m < 4; m++) {
            i32x4 lo = *(const i32x4*)(smem + aOffL[m]);
            i32x4 hi = *(const i32x4*)(smem + aOffH[m]);
            a[m] = (i32x8){lo[0], lo[1], lo[2], lo[3], hi[0], hi[1], hi[2], hi[3]};
        }
#pragma unroll
        for (int n = 0; n < 4; n++) {
            i32x4 lo = *(const i32x4*)(smem + bOffL[n]);
            i32x4 hi = *(const i32x4*)(smem + bOffH[n]);
            b[n] = (i32x8){lo[0], lo[1], lo[2], lo[3], hi[0], hi[1], hi[2], hi[3]};
        }
        // SWAPPED: train-frag as A-operand, query-frag as B-operand -> D = S^T
#pragma unroll
        for (int m = 0; m < 4; m++)
#pragma unroll
            for (int n = 0; n < 4; n++)
                acc[m][n] = __builtin_amdgcn_mfma_scale_f32_16x16x128_f8f6f4(
                    b[m], a[n], acc[m][n],
                    0, 0, 0, 0x7F7F7F7Fu, 0, 0x7F7F7F7Fu);
    }
    // no post-loop barrier needed: no further LDS use

    // ---- register epilogue: per-query top-4 of this wave's 64 trains ----
    const int tq = colTile * BN + wc * 64 + (lane >> 4) * 4;   // + mt*16 + r
    float4 tsv[4];
#pragma unroll
    for (int mt = 0; mt < 4; mt++)
        tsv[mt] = *reinterpret_cast<const float4*>(tsq + tq + mt * 16);

    uint4 outv;
#pragma unroll
    for (int nq = 0; nq < 4; nq++) {
        unsigned m1 = ~0u, m2 = ~0u, m3 = ~0u, m4 = ~0u;
#pragma unroll
        for (int mt = 0; mt < 4; mt++) {
            const float* tv = (const float*)&tsv[mt];
#pragma unroll
            for (int r = 0; r < 4; r++) {
                float key = fmaf(-2.f, acc[mt][nq][r], tv[r]);
                unsigned v = (pack32(key) & 0xFFFF0000u) | (unsigned)(tq + mt * 16 + r);
                unsigned t0, t1, t2;
                t0 = max(m1, v);  m1 = min(m1, v);
                t1 = max(m2, t0); m2 = min(m2, t0);
                t2 = max(m3, t1); m3 = min(m3, t1);
                m4 = min(m4, t2);
            }
        }
        // butterfly merges across the 4 lane-groups holding this query's trains
#pragma unroll
        for (int off = 16; off <= 32; off <<= 1) {
            unsigned o1 = (unsigned)__shfl_xor((int)m1, off);
            unsigned o2 = (unsigned)__shfl_xor((int)m2, off);
            unsigned o3 = (unsigned)__shfl_xor((int)m3, off);
            unsigned o4 = (unsigned)__shfl_xor((int)m4, off);
            unsigned a1 = min(m1, o4), a2 = min(m2, o3);
            unsigned a3 = min(m3, o2), a4 = min(m4, o1);
            unsigned t;
            t = min(a1, a3); a3 = max(a1, a3); a1 = t;
            t = min(a2, a4); a4 = max(a2, a4); a2 = t;
            t = min(a1, a2); a2 = max(a1, a2); a1 = t;
            t = min(a3, a4); a4 = max(a3, a4); a3 = t;
            m1 = a1; m2 = a2; m3 = a3; m4 = a4;
        }
        if ((lane >> 4) == nq) outv = (uint4){m1, m2, m3, m4};
    }
    // lane's query: q = wr*64 + (lane>>4)*16 + (lane&15) = wr*64 + lane
    *reinterpret_cast<uint4*>(
        cand + ((size_t)(rowTile * BM + wr * 64 + lane) * NCT + colTile) * TSEL + wc * 4) = outv;
}

// ---------------- Kernel 3: per-wave top-8 -> exact fp32 re-rank (32) -> top-7 mean ----------------
__global__ void __launch_bounds__(256) knn_reduce_kernel(
    const float* __restrict__ X, const float* __restrict__ Xt,
    const float* __restrict__ tsq, const float* __restrict__ y,
    const unsigned* __restrict__ cand, float* __restrict__ out) {
    __shared__ float xrow[D];
    __shared__ float red[4];
    __shared__ unsigned sel[32];
    __shared__ float exd[32];
    __shared__ unsigned exi[32];
    __shared__ float ys[32];
    const int q = blockIdx.x;
    const int tid = threadIdx.x;
    const int lane = tid & 63, wave = tid >> 6;

    if (tid < D / 4)
        ((float4*)xrow)[tid] = ((const float4*)(X + (size_t)q * D))[tid];

    const unsigned* cq = cand + (size_t)q * (NCT * TSEL) + wave * 1024 + lane * 4;
    unsigned v[16];
    {
        uint4 a = *(const uint4*)(cq);
        uint4 b = *(const uint4*)(cq + 256);
        uint4 c = *(const uint4*)(cq + 512);
        uint4 d = *(const uint4*)(cq + 768);
        v[0] = a.x;  v[1] = a.y;  v[2] = a.z;  v[3] = a.w;
        v[4] = b.x;  v[5] = b.y;  v[6] = b.z;  v[7] = b.w;
        v[8] = c.x;  v[9] = c.y;  v[10] = c.z; v[11] = c.w;
        v[12] = d.x; v[13] = d.y; v[14] = d.z; v[15] = d.w;
    }

#pragma unroll
    for (int r = 0; r < 8; ++r) {
        unsigned lm = v[0];
#pragma unroll
        for (int i = 1; i < 16; ++i) lm = min(lm, v[i]);
        unsigned wm = lm;
#pragma unroll
        for (int off = 1; off < 64; off <<= 1) {
            unsigned o = (unsigned)__shfl_xor((int)wm, off);
            wm = min(wm, o);
        }
        if (lane == 0) sel[wave * 8 + r] = wm;
        if (lm == wm) {
            bool done = false;
#pragma unroll
            for (int i = 0; i < 16; ++i)
                if (!done && v[i] == wm) { v[i] = 0xFFFFFFFFu; done = true; }
        }
    }
    __syncthreads();

    float xs = 0.f;
#pragma unroll
    for (int j = 0; j < 3; j++) { float t = xrow[tid + j * 256]; xs = fmaf(t, t, xs); }
#pragma unroll
    for (int off = 32; off; off >>= 1) xs += __shfl_down(xs, off);
    if (lane == 0) red[wave] = xs;
    __syncthreads();
    const float xsqs = red[0] + red[1] + red[2] + red[3];

    {
        const int c = tid >> 3, p = tid & 7;
        const unsigned id = sel[c] & 0xFFFFu;
        const float4* t4 = (const float4*)(Xt + (size_t)id * D);
        const float4* x4 = (const float4*)xrow;
        float s = 0.f;
#pragma unroll
        for (int k = 0; k < 24; ++k) {
            float4 a = x4[p + 8 * k];
            float4 b = t4[p + 8 * k];
            s = fmaf(a.x, b.x, fmaf(a.y, b.y, fmaf(a.z, b.z, fmaf(a.w, b.w, s))));
        }
        s += __shfl_xor(s, 1); s += __shfl_xor(s, 2); s += __shfl_xor(s, 4);
        if (p == 0) {
            float d2 = xsqs + tsq[id] - 2.f * s;
            exd[c] = sqrtf(fmaxf(d2, 0.f));
            exi[c] = id;
            ys[c] = y[id];
        }
    }
    __syncthreads();

    if (wave == 0) {
        unsigned long long p;
        float myy = 0.f;
        if (lane < 32) {
            p = ((unsigned long long)pack32(exd[lane]) << 32) | exi[lane];
            myy = ys[lane];
        } else {
            p = ~0ull;
        }
        float acc = 0.f;
        for (int r = 0; r < KNN; ++r) {
            unsigned long long m = p;
#pragma unroll
            for (int off = 1; off < 64; off <<= 1) {
                unsigned long long o = shfl_xor64(m, off);
                m = o < m ? o : m;
            }
            if (p == m) { acc += myy; p = ~0ull; }
        }
#pragma unroll
        for (int off = 32; off; off >>= 1) acc += __shfl_down(acc, off);
        if (lane == 0) out[q] = acc / 7.0f;
    }
}

extern "C" void kernel_launch(void* const* d_in, const int* in_sizes, int n_in,
                              void* d_out, int out_size, void* d_ws, size_t ws_size,
                              hipStream_t stream) {
    const float* X  = (const float*)d_in[0];
    const float* Xt = (const float*)d_in[1];
    const float* y  = (const float*)d_in[2];
    float* out = (float*)d_out;
    char* ws = (char*)d_ws;
    unsigned* Xb8 = (unsigned*)(ws + XB_OFF);
    unsigned* Tb8 = (unsigned*)(ws + TB_OFF);
    float* tsq = (float*)(ws + TSQ_OFF);
    unsigned* cand = (unsigned*)(ws + CAND_OFF);

    prep_kernel<<<dim3(Q + NTRAIN), dim3(192), 0, stream>>>(X, Xt, Xb8, Tb8, tsq);
    knn_gemm_kernel<<<dim3(Q / BM, NCT), dim3(256), 0, stream>>>(
        (const unsigned char*)Xb8, (const unsigned char*)Tb8, tsq, cand);
    knn_reduce_kernel<<<dim3(Q), dim3(256), 0, stream>>>(X, Xt, tsq, y, cand, out);
}